// Round 5
// baseline (1038.419 us; speedup 1.0000x reference)
//
#include <hip/hip_runtime.h>

#define TLEN 512
#define HD 128
#define VOC 50000

typedef short bvec8 __attribute__((ext_vector_type(8)));   // 8 bf16 (4 VGPRs)
typedef float fvec4 __attribute__((ext_vector_type(4)));   // f32 MFMA accumulator
typedef int   ivec4 __attribute__((ext_vector_type(4)));   // 16B LDS read
typedef int   ivec8 __attribute__((ext_vector_type(8)));   // 32 fp8 = f8f6f4 operand

__device__ __forceinline__ unsigned short f2bf(float f){
  unsigned u = __builtin_bit_cast(unsigned, f);
  u += 0x7fffu + ((u >> 16) & 1u);
  return (unsigned short)(u >> 16);
}

__device__ __forceinline__ float fsig(float a){
  return __builtin_amdgcn_rcpf(1.f + __builtin_amdgcn_exp2f(-1.44269504f * a));
}

// ---------------- emb fp32 -> bf16 table ----------------
__global__ void emb_cvt(const float* __restrict__ emb, unsigned short* __restrict__ out, int n4){
  int i = blockIdx.x * blockDim.x + threadIdx.x;
  if (i < n4){
    float4 v = *(const float4*)(emb + (size_t)i * 4);
    ushort4 o;
    o.x = f2bf(v.x); o.y = f2bf(v.y); o.z = f2bf(v.z); o.w = f2bf(v.w);
    *(ushort4*)(out + (size_t)i * 4) = o;
  }
}

// ---------------- persistent bidirectional GRU scan ----------------
// 512 blocks: 0..255 fwd, 256..511 bwd; 2 batch rows each; 8 waves; 64KB LDS
// -> exactly 2 independent blocks (chains) per CU to hide per-step latency.
// Batches at tile rows {0,4}; tile rows 8..15 duplicate 0..7 (harmless copies).
// xp (x@W+bias): bf16 MFMA, 4 timesteps packed/tile, woven 1 K-slice/step.
// recurrence (h@U): fp8 e4m3 via mfma_scale 16x16x128 (unit scales), 1 MFMA/gate.
__global__ __launch_bounds__(512, 4) void gru_scan(
    const int* __restrict__ tokens, const unsigned short* __restrict__ embb,
    const float* __restrict__ Wf, const float* __restrict__ Uf, const float* __restrict__ bfv,
    const float* __restrict__ Wb, const float* __restrict__ Ub, const float* __restrict__ bbv,
    float* __restrict__ hbuf)
{
  const int tid  = threadIdx.x;
  const int wid  = tid >> 6, lane = tid & 63;
  const int l15  = lane & 15, l4 = lane >> 4;
  const int dir  = blockIdx.x >> 8, grp = blockIdx.x & 255;
  const int cw   = wid * 16 + l15;                 // gate column in [0,128)

  const float* __restrict__ W  = dir ? Wb : Wf;
  const float* __restrict__ U  = dir ? Ub : Uf;
  const float* __restrict__ bv = dir ? bbv : bfv;

  // 64 KB -> exactly 2 blocks/CU. Two fp8 h buffers (16 rows x 144B) at 0 / 4096.
  __shared__ __attribute__((aligned(16))) unsigned char hl[65536];

  // ---- bf16 xp B-frags: W only (K=128, 4 K-tiles) ----
  bvec8 Bz[4], Br[4], Bh[4];
#pragma unroll
  for (int kt = 0; kt < 4; ++kt){
#pragma unroll
    for (int j = 0; j < 8; ++j){
      const int k = kt * 32 + l4 * 8 + j;
      Bz[kt][j] = (short)f2bf(W[k * 384 + cw]);
      Br[kt][j] = (short)f2bf(W[k * 384 + 128 + cw]);
      Bh[kt][j] = (short)f2bf(W[k * 384 + 256 + cw]);
    }
  }

  // ---- fp8 recurrent B-frags: U, e4m3. lane(l4,l15): col=cw, k = l4*32 + j ----
  ivec8 Qz, Qr, Qh;
#pragma unroll
  for (int w = 0; w < 8; ++w){
    const int k0 = l4 * 32 + w * 4;
    int vz = __builtin_amdgcn_cvt_pk_fp8_f32(U[(k0+0)*384 + cw], U[(k0+1)*384 + cw], 0, 0);
    vz     = __builtin_amdgcn_cvt_pk_fp8_f32(U[(k0+2)*384 + cw], U[(k0+3)*384 + cw], vz, 1);
    int vr = __builtin_amdgcn_cvt_pk_fp8_f32(U[(k0+0)*384 + 128 + cw], U[(k0+1)*384 + 128 + cw], 0, 0);
    vr     = __builtin_amdgcn_cvt_pk_fp8_f32(U[(k0+2)*384 + 128 + cw], U[(k0+3)*384 + 128 + cw], vr, 1);
    int vh = __builtin_amdgcn_cvt_pk_fp8_f32(U[(k0+0)*384 + 256 + cw], U[(k0+1)*384 + 256 + cw], 0, 0);
    vh     = __builtin_amdgcn_cvt_pk_fp8_f32(U[(k0+2)*384 + 256 + cw], U[(k0+3)*384 + 256 + cw], vh, 1);
    Qz[w] = vz; Qr[w] = vr; Qh[w] = vh;
  }

  const float bzs = bv[cw] + bv[384 + cw];
  const float brs = bv[128 + cw] + bv[384 + 128 + cw];
  const float bix = bv[256 + cw];
  const float buh = bv[384 + 256 + cw];
  const fvec4 ZF  = {0.f, 0.f, 0.f, 0.f};

  for (int i = tid; i < 2048; i += 512) ((int*)hl)[i] = 0;   // zero both h buffers
  float h0 = 0.f;                                            // h[batch l4][cw] fp32 master

  // x gather: xp tile row = 4*batch + step_in_group; rows 8..15 duplicate 0..7
  const int  brow = (l15 >> 2) & 1, srow = l15 & 3;
  const long tbx  = (long)(grp * 2 + brow) * TLEN;
  const int  tb0  = dir ? (TLEN - 1) : 0, tsg = dir ? -1 : 1;
  auto tix = [&](int t){ t = (t > TLEN - 1) ? (TLEN - 1) : t; return tb0 + tsg * t; };

  bvec8 xA[4], xB[4];
  fvec4 xZ = {bzs, bzs, bzs, bzs}, xR = {brs, brs, brs, brs}, xX = {bix, bix, bix, bix};
  fvec4 nZ, nR, nX;
  {
    const bvec8* p0 = (const bvec8*)(embb + (size_t)tokens[tbx + tix(srow)] * HD);
#pragma unroll
    for (int kt = 0; kt < 4; ++kt) xB[kt] = p0[kt * 4 + l4];
#pragma unroll
    for (int kt = 0; kt < 4; ++kt){
      xZ = __builtin_amdgcn_mfma_f32_16x16x32_bf16(xB[kt], Bz[kt], xZ, 0, 0, 0);
      xR = __builtin_amdgcn_mfma_f32_16x16x32_bf16(xB[kt], Br[kt], xR, 0, 0, 0);
      xX = __builtin_amdgcn_mfma_f32_16x16x32_bf16(xB[kt], Bh[kt], xX, 0, 0, 0);
    }
    const bvec8* p1 = (const bvec8*)(embb + (size_t)tokens[tbx + tix(4 + srow)] * HD);
#pragma unroll
    for (int kt = 0; kt < 4; ++kt) xA[kt] = p1[kt * 4 + l4];
  }
  int tok2 = tokens[tbx + tix(8 + srow)];
  nZ = (fvec4){bzs, bzs, bzs, bzs}; nR = (fvec4){brs, brs, brs, brs}; nX = (fvec4){bix, bix, bix, bix};

  const int hrd = l15 * 144 + l4 * 32;            // fp8 A-frag base (byte)
  const int wb  = (4 * l4) * 144 + cw;            // h write slot (byte)
  __syncthreads();

#define STEP(S, P, XF) { \
    ivec4 alo = *(const ivec4*)&hl[(P) + hrd]; \
    ivec4 ahi = *(const ivec4*)&hl[(P) + hrd + 16]; \
    nZ = __builtin_amdgcn_mfma_f32_16x16x32_bf16(XF[S], Bz[S], nZ, 0, 0, 0); \
    nR = __builtin_amdgcn_mfma_f32_16x16x32_bf16(XF[S], Br[S], nR, 0, 0, 0); \
    nX = __builtin_amdgcn_mfma_f32_16x16x32_bf16(XF[S], Bh[S], nX, 0, 0, 0); \
    ivec8 af = __builtin_shufflevector(alo, ahi, 0, 1, 2, 3, 4, 5, 6, 7); \
    fvec4 aZ = __builtin_amdgcn_mfma_scale_f32_16x16x128_f8f6f4(af, Qz, ZF, 0, 0, 0, 0x7F7F7F7F, 0, 0x7F7F7F7F); \
    fvec4 aR = __builtin_amdgcn_mfma_scale_f32_16x16x128_f8f6f4(af, Qr, ZF, 0, 0, 0, 0x7F7F7F7F, 0, 0x7F7F7F7F); \
    fvec4 aU = __builtin_amdgcn_mfma_scale_f32_16x16x128_f8f6f4(af, Qh, ZF, 0, 0, 0, 0x7F7F7F7F, 0, 0x7F7F7F7F); \
    float zz = fsig(xZ[S] + aZ[0]); \
    float rg = fsig(xR[S] + aR[0]); \
    float ar = xX[S] + rg * (aU[0] + buh); ar = fmaxf(ar, -30.f); \
    float y  = __builtin_amdgcn_exp2f(-2.88539008f * ar); \
    float th = (1.f - y) * __builtin_amdgcn_rcpf(1.f + y); \
    h0 = th + zz * (h0 - th); \
    hl[((P) ^ 4096) + wb] = (unsigned char)(__builtin_amdgcn_cvt_pk_fp8_f32(h0, h0, 0, 0) & 0xff); \
    asm volatile("s_waitcnt lgkmcnt(0)" ::: "memory"); \
    __builtin_amdgcn_s_barrier(); \
  }

  for (int g = 0; g < 128; g += 2){
    {   // emb frags for group g+2 -> xB
      const bvec8* pn = (const bvec8*)(embb + (size_t)tok2 * HD);
#pragma unroll
      for (int kt = 0; kt < 4; ++kt) xB[kt] = pn[kt * 4 + l4];
      tok2 = tokens[tbx + tix(4 * (g + 3) + srow)];
    }
    STEP(0, 0, xA) STEP(1, 4096, xA) STEP(2, 0, xA) STEP(3, 4096, xA)
    xZ = nZ; xR = nR; xX = nX;
    nZ = (fvec4){bzs, bzs, bzs, bzs}; nR = (fvec4){brs, brs, brs, brs}; nX = (fvec4){bix, bix, bix, bix};
    {   // emb frags for group g+3 -> xA
      const bvec8* pn = (const bvec8*)(embb + (size_t)tok2 * HD);
#pragma unroll
      for (int kt = 0; kt < 4; ++kt) xA[kt] = pn[kt * 4 + l4];
      tok2 = tokens[tbx + tix(4 * (g + 4) + srow)];
    }
    STEP(0, 0, xB) STEP(1, 4096, xB) STEP(2, 0, xB) STEP(3, 4096, xB)
    xZ = nZ; xR = nR; xX = nX;
    nZ = (fvec4){bzs, bzs, bzs, bzs}; nR = (fvec4){brs, brs, brs, brs}; nX = (fvec4){bix, bix, bix, bix};
  }
#undef STEP

  // final state: lanes l4<2 hold real batches (tile rows 0,4)
  if (l4 < 2)
    hbuf[(size_t)(grp * 2 + l4) * 256 + dir * 128 + cw] = h0;
}

// ---------------- head: sigmoid(hcat @ Wd + bd) ----------------
__global__ void head_k(const float* __restrict__ hbuf, const float* __restrict__ Wd,
                       const float* __restrict__ bd, float* __restrict__ out){
  const int wid = threadIdx.x >> 6, lane = threadIdx.x & 63;
  const int b = blockIdx.x * 4 + wid;
  const float* hr = hbuf + (size_t)b * 256;
  float s = 0.f;
#pragma unroll
  for (int j = 0; j < 4; ++j){ const int k = j * 64 + lane; s += hr[k] * Wd[k]; }
#pragma unroll
  for (int off = 32; off > 0; off >>= 1) s += __shfl_down(s, off);
  if (lane == 0) out[b] = 1.f / (1.f + __expf(-(s + bd[0])));
}

extern "C" void kernel_launch(void* const* d_in, const int* in_sizes, int n_in,
                              void* d_out, int out_size, void* d_ws, size_t ws_size,
                              hipStream_t stream){
  const int*   tokens = (const int*)  d_in[0];
  const float* emb    = (const float*)d_in[1];
  const float* Wf     = (const float*)d_in[2];
  const float* Uf     = (const float*)d_in[3];
  const float* bf_    = (const float*)d_in[4];
  const float* Wb     = (const float*)d_in[5];
  const float* Ub     = (const float*)d_in[6];
  const float* bb_    = (const float*)d_in[7];
  const float* Wd     = (const float*)d_in[8];
  const float* bd     = (const float*)d_in[9];
  float* out = (float*)d_out;

  unsigned short* embb = (unsigned short*)d_ws;                       // 12.8 MB bf16 table
  float* hbuf = (float*)((char*)d_ws + (size_t)VOC * HD * sizeof(unsigned short)); // 512 KB

  const int n4 = VOC * HD / 4;
  emb_cvt<<<(n4 + 255) / 256, 256, 0, stream>>>(emb, embb, n4);
  gru_scan<<<512, 512, 0, stream>>>(tokens, embb, Wf, Uf, bf_, Wb, Ub, bb_, hbuf);
  head_k<<<128, 256, 0, stream>>>(hbuf, Wd, bd, out);
}

// Round 6
// 477.891 us; speedup vs baseline: 2.1729x; 2.1729x over previous
//
#include <hip/hip_runtime.h>

#define TLEN 512
#define HD 128
#define VOC 50000

typedef short bvec8 __attribute__((ext_vector_type(8)));   // 8 bf16 (4 VGPRs)
typedef float fvec4 __attribute__((ext_vector_type(4)));   // f32 MFMA accumulator
typedef int   ivec4 __attribute__((ext_vector_type(4)));   // 16B LDS read
typedef int   ivec8 __attribute__((ext_vector_type(8)));   // 32 fp8 = f8f6f4 operand

__device__ __forceinline__ unsigned short f2bf(float f){
  unsigned u = __builtin_bit_cast(unsigned, f);
  u += 0x7fffu + ((u >> 16) & 1u);
  return (unsigned short)(u >> 16);
}

__device__ __forceinline__ float fsig(float a){
  return __builtin_amdgcn_rcpf(1.f + __builtin_amdgcn_exp2f(-1.44269504f * a));
}

// ---------------- emb fp32 -> bf16 table ----------------
__global__ void emb_cvt(const float* __restrict__ emb, unsigned short* __restrict__ out, int n4){
  int i = blockIdx.x * blockDim.x + threadIdx.x;
  if (i < n4){
    float4 v = *(const float4*)(emb + (size_t)i * 4);
    ushort4 o;
    o.x = f2bf(v.x); o.y = f2bf(v.y); o.z = f2bf(v.z); o.w = f2bf(v.w);
    *(ushort4*)(out + (size_t)i * 4) = o;
  }
}

// ---------------- persistent bidirectional GRU scan ----------------
// 512 blocks: 0..255 fwd, 256..511 bwd; 2 batch rows each; 8 waves; 64KB LDS
// -> 2 independent blocks (chains) per CU (LDS-legal; needs <=128 VGPR).
// NOTE: __launch_bounds__(512,2) NOT (512,4): the 4-band forced the allocator
// to 64 VGPRs and spilled the weight set to scratch (round 5: 4 GB HBM traffic).
// Batches at tile rows {0,4}; tile rows 8..15 duplicate 0..7 (harmless copies).
// xp (x@W+bias): bf16 MFMA, 4 timesteps packed/tile, woven 1 K-slice/step.
// recurrence (h@U): fp8 e4m3 via mfma_scale 16x16x128 (unit scales), 1 MFMA/gate.
__global__ __launch_bounds__(512, 2) void gru_scan(
    const int* __restrict__ tokens, const unsigned short* __restrict__ embb,
    const float* __restrict__ Wf, const float* __restrict__ Uf, const float* __restrict__ bfv,
    const float* __restrict__ Wb, const float* __restrict__ Ub, const float* __restrict__ bbv,
    float* __restrict__ hbuf)
{
  const int tid  = threadIdx.x;
  const int wid  = tid >> 6, lane = tid & 63;
  const int l15  = lane & 15, l4 = lane >> 4;
  const int dir  = blockIdx.x >> 8, grp = blockIdx.x & 255;
  const int cw   = wid * 16 + l15;                 // gate column in [0,128)

  const float* __restrict__ W  = dir ? Wb : Wf;
  const float* __restrict__ U  = dir ? Ub : Uf;
  const float* __restrict__ bv = dir ? bbv : bfv;

  // 64 KB -> 2 blocks/CU. Two fp8 h buffers (16 rows x 144B) at 0 / 4096.
  __shared__ __attribute__((aligned(16))) unsigned char hl[65536];

  // ---- bf16 xp B-frags: W only (K=128, 4 K-tiles) ----
  bvec8 Bz[4], Br[4], Bh[4];
#pragma unroll
  for (int kt = 0; kt < 4; ++kt){
#pragma unroll
    for (int j = 0; j < 8; ++j){
      const int k = kt * 32 + l4 * 8 + j;
      Bz[kt][j] = (short)f2bf(W[k * 384 + cw]);
      Br[kt][j] = (short)f2bf(W[k * 384 + 128 + cw]);
      Bh[kt][j] = (short)f2bf(W[k * 384 + 256 + cw]);
    }
  }

  // ---- fp8 recurrent B-frags: U, e4m3. lane(l4,l15): col=cw, k = l4*32 + j ----
  ivec8 Qz, Qr, Qh;
#pragma unroll
  for (int w = 0; w < 8; ++w){
    const int k0 = l4 * 32 + w * 4;
    int vz = __builtin_amdgcn_cvt_pk_fp8_f32(U[(k0+0)*384 + cw], U[(k0+1)*384 + cw], 0, 0);
    vz     = __builtin_amdgcn_cvt_pk_fp8_f32(U[(k0+2)*384 + cw], U[(k0+3)*384 + cw], vz, 1);
    int vr = __builtin_amdgcn_cvt_pk_fp8_f32(U[(k0+0)*384 + 128 + cw], U[(k0+1)*384 + 128 + cw], 0, 0);
    vr     = __builtin_amdgcn_cvt_pk_fp8_f32(U[(k0+2)*384 + 128 + cw], U[(k0+3)*384 + 128 + cw], vr, 1);
    int vh = __builtin_amdgcn_cvt_pk_fp8_f32(U[(k0+0)*384 + 256 + cw], U[(k0+1)*384 + 256 + cw], 0, 0);
    vh     = __builtin_amdgcn_cvt_pk_fp8_f32(U[(k0+2)*384 + 256 + cw], U[(k0+3)*384 + 256 + cw], vh, 1);
    Qz[w] = vz; Qr[w] = vr; Qh[w] = vh;
  }

  const float bzs = bv[cw] + bv[384 + cw];
  const float brs = bv[128 + cw] + bv[384 + 128 + cw];
  const float bix = bv[256 + cw];
  const float buh = bv[384 + 256 + cw];
  const fvec4 ZF  = {0.f, 0.f, 0.f, 0.f};

  for (int i = tid; i < 2048; i += 512) ((int*)hl)[i] = 0;   // zero both h buffers
  float h0 = 0.f;                                            // h[batch l4][cw] fp32 master

  // x gather: xp tile row = 4*batch + step_in_group; rows 8..15 duplicate 0..7
  const int  brow = (l15 >> 2) & 1, srow = l15 & 3;
  const long tbx  = (long)(grp * 2 + brow) * TLEN;
  const int  tb0  = dir ? (TLEN - 1) : 0, tsg = dir ? -1 : 1;
  auto tix = [&](int t){ t = (t > TLEN - 1) ? (TLEN - 1) : t; return tb0 + tsg * t; };

  bvec8 xA[4], xB[4];
  fvec4 xZ = {bzs, bzs, bzs, bzs}, xR = {brs, brs, brs, brs}, xX = {bix, bix, bix, bix};
  fvec4 nZ, nR, nX;
  {
    const bvec8* p0 = (const bvec8*)(embb + (size_t)tokens[tbx + tix(srow)] * HD);
#pragma unroll
    for (int kt = 0; kt < 4; ++kt) xB[kt] = p0[kt * 4 + l4];
#pragma unroll
    for (int kt = 0; kt < 4; ++kt){
      xZ = __builtin_amdgcn_mfma_f32_16x16x32_bf16(xB[kt], Bz[kt], xZ, 0, 0, 0);
      xR = __builtin_amdgcn_mfma_f32_16x16x32_bf16(xB[kt], Br[kt], xR, 0, 0, 0);
      xX = __builtin_amdgcn_mfma_f32_16x16x32_bf16(xB[kt], Bh[kt], xX, 0, 0, 0);
    }
    const bvec8* p1 = (const bvec8*)(embb + (size_t)tokens[tbx + tix(4 + srow)] * HD);
#pragma unroll
    for (int kt = 0; kt < 4; ++kt) xA[kt] = p1[kt * 4 + l4];
  }
  int tok2 = tokens[tbx + tix(8 + srow)];
  nZ = (fvec4){bzs, bzs, bzs, bzs}; nR = (fvec4){brs, brs, brs, brs}; nX = (fvec4){bix, bix, bix, bix};

  const int hrd = l15 * 144 + l4 * 32;            // fp8 A-frag base (byte)
  const int wb  = (4 * l4) * 144 + cw;            // h write slot (byte)
  __syncthreads();

#define STEP(S, P, XF) { \
    ivec4 alo = *(const ivec4*)&hl[(P) + hrd]; \
    ivec4 ahi = *(const ivec4*)&hl[(P) + hrd + 16]; \
    nZ = __builtin_amdgcn_mfma_f32_16x16x32_bf16(XF[S], Bz[S], nZ, 0, 0, 0); \
    nR = __builtin_amdgcn_mfma_f32_16x16x32_bf16(XF[S], Br[S], nR, 0, 0, 0); \
    nX = __builtin_amdgcn_mfma_f32_16x16x32_bf16(XF[S], Bh[S], nX, 0, 0, 0); \
    ivec8 af = __builtin_shufflevector(alo, ahi, 0, 1, 2, 3, 4, 5, 6, 7); \
    fvec4 aZ = __builtin_amdgcn_mfma_scale_f32_16x16x128_f8f6f4(af, Qz, ZF, 0, 0, 0, 0x7F7F7F7F, 0, 0x7F7F7F7F); \
    fvec4 aR = __builtin_amdgcn_mfma_scale_f32_16x16x128_f8f6f4(af, Qr, ZF, 0, 0, 0, 0x7F7F7F7F, 0, 0x7F7F7F7F); \
    fvec4 aU = __builtin_amdgcn_mfma_scale_f32_16x16x128_f8f6f4(af, Qh, ZF, 0, 0, 0, 0x7F7F7F7F, 0, 0x7F7F7F7F); \
    float zz = fsig(xZ[S] + aZ[0]); \
    float rg = fsig(xR[S] + aR[0]); \
    float ar = xX[S] + rg * (aU[0] + buh); ar = fmaxf(ar, -30.f); \
    float y  = __builtin_amdgcn_exp2f(-2.88539008f * ar); \
    float th = (1.f - y) * __builtin_amdgcn_rcpf(1.f + y); \
    h0 = th + zz * (h0 - th); \
    hl[((P) ^ 4096) + wb] = (unsigned char)(__builtin_amdgcn_cvt_pk_fp8_f32(h0, h0, 0, 0) & 0xff); \
    asm volatile("s_waitcnt lgkmcnt(0)" ::: "memory"); \
    __builtin_amdgcn_s_barrier(); \
  }

  for (int g = 0; g < 128; g += 2){
    {   // emb frags for group g+2 -> xB
      const bvec8* pn = (const bvec8*)(embb + (size_t)tok2 * HD);
#pragma unroll
      for (int kt = 0; kt < 4; ++kt) xB[kt] = pn[kt * 4 + l4];
      tok2 = tokens[tbx + tix(4 * (g + 3) + srow)];
    }
    STEP(0, 0, xA) STEP(1, 4096, xA) STEP(2, 0, xA) STEP(3, 4096, xA)
    xZ = nZ; xR = nR; xX = nX;
    nZ = (fvec4){bzs, bzs, bzs, bzs}; nR = (fvec4){brs, brs, brs, brs}; nX = (fvec4){bix, bix, bix, bix};
    {   // emb frags for group g+3 -> xA
      const bvec8* pn = (const bvec8*)(embb + (size_t)tok2 * HD);
#pragma unroll
      for (int kt = 0; kt < 4; ++kt) xA[kt] = pn[kt * 4 + l4];
      tok2 = tokens[tbx + tix(4 * (g + 4) + srow)];
    }
    STEP(0, 0, xB) STEP(1, 4096, xB) STEP(2, 0, xB) STEP(3, 4096, xB)
    xZ = nZ; xR = nR; xX = nX;
    nZ = (fvec4){bzs, bzs, bzs, bzs}; nR = (fvec4){brs, brs, brs, brs}; nX = (fvec4){bix, bix, bix, bix};
  }
#undef STEP

  // final state: lanes l4<2 hold real batches (tile rows 0,4)
  if (l4 < 2)
    hbuf[(size_t)(grp * 2 + l4) * 256 + dir * 128 + cw] = h0;
}

// ---------------- head: sigmoid(hcat @ Wd + bd) ----------------
__global__ void head_k(const float* __restrict__ hbuf, const float* __restrict__ Wd,
                       const float* __restrict__ bd, float* __restrict__ out){
  const int wid = threadIdx.x >> 6, lane = threadIdx.x & 63;
  const int b = blockIdx.x * 4 + wid;
  const float* hr = hbuf + (size_t)b * 256;
  float s = 0.f;
#pragma unroll
  for (int j = 0; j < 4; ++j){ const int k = j * 64 + lane; s += hr[k] * Wd[k]; }
#pragma unroll
  for (int off = 32; off > 0; off >>= 1) s += __shfl_down(s, off);
  if (lane == 0) out[b] = 1.f / (1.f + __expf(-(s + bd[0])));
}

extern "C" void kernel_launch(void* const* d_in, const int* in_sizes, int n_in,
                              void* d_out, int out_size, void* d_ws, size_t ws_size,
                              hipStream_t stream){
  const int*   tokens = (const int*)  d_in[0];
  const float* emb    = (const float*)d_in[1];
  const float* Wf     = (const float*)d_in[2];
  const float* Uf     = (const float*)d_in[3];
  const float* bf_    = (const float*)d_in[4];
  const float* Wb     = (const float*)d_in[5];
  const float* Ub     = (const float*)d_in[6];
  const float* bb_    = (const float*)d_in[7];
  const float* Wd     = (const float*)d_in[8];
  const float* bd     = (const float*)d_in[9];
  float* out = (float*)d_out;

  unsigned short* embb = (unsigned short*)d_ws;                       // 12.8 MB bf16 table
  float* hbuf = (float*)((char*)d_ws + (size_t)VOC * HD * sizeof(unsigned short)); // 512 KB

  const int n4 = VOC * HD / 4;
  emb_cvt<<<(n4 + 255) / 256, 256, 0, stream>>>(emb, embb, n4);
  gru_scan<<<512, 512, 0, stream>>>(tokens, embb, Wf, Uf, bf_, Wb, Ub, bb_, hbuf);
  head_k<<<128, 256, 0, stream>>>(hbuf, Wd, bd, out);
}

// Round 7
// 369.738 us; speedup vs baseline: 2.8085x; 1.2925x over previous
//
#include <hip/hip_runtime.h>

#define TLEN 512
#define HD 128
#define VOC 50000

typedef short bvec8 __attribute__((ext_vector_type(8)));   // 8 bf16 (4 VGPRs)
typedef float fvec4 __attribute__((ext_vector_type(4)));   // f32 MFMA accumulator
typedef int   ivec4 __attribute__((ext_vector_type(4)));   // 16B LDS read
typedef int   ivec8 __attribute__((ext_vector_type(8)));   // 32 fp8 = f8f6f4 operand

__device__ __forceinline__ unsigned short f2bf(float f){
  unsigned u = __builtin_bit_cast(unsigned, f);
  u += 0x7fffu + ((u >> 16) & 1u);
  return (unsigned short)(u >> 16);
}

__device__ __forceinline__ float fsig(float a){
  return __builtin_amdgcn_rcpf(1.f + __builtin_amdgcn_exp2f(-1.44269504f * a));
}

// ---------------- emb fp32 -> bf16 table ----------------
__global__ void emb_cvt(const float* __restrict__ emb, unsigned short* __restrict__ out, int n4){
  int i = blockIdx.x * blockDim.x + threadIdx.x;
  if (i < n4){
    float4 v = *(const float4*)(emb + (size_t)i * 4);
    ushort4 o;
    o.x = f2bf(v.x); o.y = f2bf(v.y); o.z = f2bf(v.z); o.w = f2bf(v.w);
    *(ushort4*)(out + (size_t)i * 4) = o;
  }
}

// ---------------- persistent bidirectional GRU scan: DUAL-CHAIN ILP ----------------
// 256 blocks (1/CU): 0..127 fwd, 128..255 bwd; 8 waves; 96KB LDS claim (force 1/CU).
// Each block runs TWO independent 2-row chains (batches 4g..4g+1, 4g+2..4g+3) with
// SHARED weight registers; their instructions interleave so chain B's issue fills
// chain A's latency bubbles (occupancy banding made TLP uncontrollable; ILP instead).
// Batches at tile rows {0,4}; rows 8..15 duplicate. xp: bf16 MFMA, 4 steps packed,
// woven 1 K-slice/step; x-frags via 2-slice rolling buffer (2-step prefetch).
// recurrence: fp8 e4m3 via mfma_scale 16x16x128 (unit scales), 1 MFMA/gate/chain.
__global__ __launch_bounds__(512, 2) void gru_scan(
    const int* __restrict__ tokens, const unsigned short* __restrict__ embb,
    const float* __restrict__ Wf, const float* __restrict__ Uf, const float* __restrict__ bfv,
    const float* __restrict__ Wb, const float* __restrict__ Ub, const float* __restrict__ bbv,
    float* __restrict__ hbuf)
{
  const int tid  = threadIdx.x;
  const int wid  = tid >> 6, lane = tid & 63;
  const int l15  = lane & 15, l4 = lane >> 4;
  const int dir  = blockIdx.x >> 7, grp = blockIdx.x & 127;
  const int cw   = wid * 16 + l15;                 // gate column in [0,128)

  const float* __restrict__ W  = dir ? Wb : Wf;
  const float* __restrict__ U  = dir ? Ub : Uf;
  const float* __restrict__ bv = dir ? bbv : bfv;

  // claim 96KB -> hard 1 block/CU; use 16KB: chainA bufs @0/4096, chainB @8192/12288
  __shared__ __attribute__((aligned(16))) unsigned char hl[98304];

  // ---- bf16 xp B-frags: W (K=128, 4 K-slices), shared by both chains ----
  bvec8 Bz[4], Br[4], Bh[4];
#pragma unroll
  for (int kt = 0; kt < 4; ++kt){
#pragma unroll
    for (int j = 0; j < 8; ++j){
      const int k = kt * 32 + l4 * 8 + j;
      Bz[kt][j] = (short)f2bf(W[k * 384 + cw]);
      Br[kt][j] = (short)f2bf(W[k * 384 + 128 + cw]);
      Bh[kt][j] = (short)f2bf(W[k * 384 + 256 + cw]);
    }
  }

  // ---- fp8 recurrent B-frags: U e4m3, shared. lane: col=cw, k = l4*32 + j ----
  ivec8 Qz, Qr, Qh;
#pragma unroll
  for (int w = 0; w < 8; ++w){
    const int k0 = l4 * 32 + w * 4;
    int vz = __builtin_amdgcn_cvt_pk_fp8_f32(U[(k0+0)*384 + cw], U[(k0+1)*384 + cw], 0, 0);
    vz     = __builtin_amdgcn_cvt_pk_fp8_f32(U[(k0+2)*384 + cw], U[(k0+3)*384 + cw], vz, 1);
    int vr = __builtin_amdgcn_cvt_pk_fp8_f32(U[(k0+0)*384 + 128 + cw], U[(k0+1)*384 + 128 + cw], 0, 0);
    vr     = __builtin_amdgcn_cvt_pk_fp8_f32(U[(k0+2)*384 + 128 + cw], U[(k0+3)*384 + 128 + cw], vr, 1);
    int vh = __builtin_amdgcn_cvt_pk_fp8_f32(U[(k0+0)*384 + 256 + cw], U[(k0+1)*384 + 256 + cw], 0, 0);
    vh     = __builtin_amdgcn_cvt_pk_fp8_f32(U[(k0+2)*384 + 256 + cw], U[(k0+3)*384 + 256 + cw], vh, 1);
    Qz[w] = vz; Qr[w] = vr; Qh[w] = vh;
  }

  const float bzs = bv[cw] + bv[384 + cw];
  const float brs = bv[128 + cw] + bv[384 + 128 + cw];
  const float bix = bv[256 + cw];
  const float buh = bv[384 + 256 + cw];
  const fvec4 ZF  = {0.f, 0.f, 0.f, 0.f};

  for (int i = tid; i < 4096; i += 512) ((int*)hl)[i] = 0;   // zero all 4 h buffers
  float h0a = 0.f, h0b = 0.f;

  // x gather mapping: xp tile row l15 -> (batch = (l15>>2)&1, step-in-group = l15&3)
  const int  brow = (l15 >> 2) & 1, srow = l15 & 3;
  const int  tbxa = (grp * 4 + brow) * TLEN;
  const int  tbxb = (grp * 4 + 2 + brow) * TLEN;
  const int  tb0  = dir ? (TLEN - 1) : 0, tsg = dir ? -1 : 1;
  auto tix = [&](int t){ t = (t > TLEN - 1) ? (TLEN - 1) : t; return tb0 + tsg * t; };
#define LDS8(tok, sl) (*(const bvec8*)(embb + (size_t)(tok) * HD + (sl) * 32 + l4 * 8))

  // group-0 xp accs computed up front (both chains)
  fvec4 xZa = {bzs,bzs,bzs,bzs}, xRa = {brs,brs,brs,brs}, xXa = {bix,bix,bix,bix};
  fvec4 xZb = {bzs,bzs,bzs,bzs}, xRb = {brs,brs,brs,brs}, xXb = {bix,bix,bix,bix};
  {
    int t0a = tokens[tbxa + tix(srow)], t0b = tokens[tbxb + tix(srow)];
#pragma unroll
    for (int kt = 0; kt < 4; ++kt){
      bvec8 fa = LDS8(t0a, kt), fb = LDS8(t0b, kt);
      xZa = __builtin_amdgcn_mfma_f32_16x16x32_bf16(fa, Bz[kt], xZa, 0,0,0);
      xRa = __builtin_amdgcn_mfma_f32_16x16x32_bf16(fa, Br[kt], xRa, 0,0,0);
      xXa = __builtin_amdgcn_mfma_f32_16x16x32_bf16(fa, Bh[kt], xXa, 0,0,0);
      xZb = __builtin_amdgcn_mfma_f32_16x16x32_bf16(fb, Bz[kt], xZb, 0,0,0);
      xRb = __builtin_amdgcn_mfma_f32_16x16x32_bf16(fb, Br[kt], xRb, 0,0,0);
      xXb = __builtin_amdgcn_mfma_f32_16x16x32_bf16(fb, Bh[kt], xXb, 0,0,0);
    }
  }
  int tokA1 = tokens[tbxa + tix(4 + srow)], tokB1 = tokens[tbxb + tix(4 + srow)];
  int tokA2 = tokens[tbxa + tix(8 + srow)], tokB2 = tokens[tbxb + tix(8 + srow)];
  bvec8 xs0a = LDS8(tokA1, 0), xs1a = LDS8(tokA1, 1);
  bvec8 xs0b = LDS8(tokB1, 0), xs1b = LDS8(tokB1, 1);
  fvec4 nZa = {bzs,bzs,bzs,bzs}, nRa = {brs,brs,brs,brs}, nXa = {bix,bix,bix,bix};
  fvec4 nZb = {bzs,bzs,bzs,bzs}, nRb = {brs,brs,brs,brs}, nXb = {bix,bix,bix,bix};

  const int hrdA = l15 * 144 + l4 * 32;           // fp8 A-frag base (byte)
  const int hrdB = hrdA + 8192;
  const int wbA  = (4 * l4) * 144 + cw;           // h write slot (byte)
  const int wbB  = wbA + 8192;
  __syncthreads();

#define GATE(XZ, XR, XX, AZ, AR, AU, H, WS) { \
    float zz = fsig(XZ[S_] + AZ[0]); \
    float rg = fsig(XR[S_] + AR[0]); \
    float ar = XX[S_] + rg * (AU[0] + buh); ar = fmaxf(ar, -30.f); \
    float y  = __builtin_amdgcn_exp2f(-2.88539008f * ar); \
    float th = (1.f - y) * __builtin_amdgcn_rcpf(1.f + y); \
    H = th + zz * (H - th); \
    hl[PX + WS] = (unsigned char)(__builtin_amdgcn_cvt_pk_fp8_f32(H, H, 0, 0) & 0xff); }

#define STEPX(S, P, XSA, XSB) { \
    const int S_ = S; const int PX = (P) ^ 4096; \
    ivec4 aloA = *(const ivec4*)&hl[(P) + hrdA]; \
    ivec4 ahiA = *(const ivec4*)&hl[(P) + hrdA + 16]; \
    ivec4 aloB = *(const ivec4*)&hl[(P) + hrdB]; \
    ivec4 ahiB = *(const ivec4*)&hl[(P) + hrdB + 16]; \
    nZa = __builtin_amdgcn_mfma_f32_16x16x32_bf16(XSA, Bz[S], nZa, 0,0,0); \
    nRa = __builtin_amdgcn_mfma_f32_16x16x32_bf16(XSA, Br[S], nRa, 0,0,0); \
    nXa = __builtin_amdgcn_mfma_f32_16x16x32_bf16(XSA, Bh[S], nXa, 0,0,0); \
    nZb = __builtin_amdgcn_mfma_f32_16x16x32_bf16(XSB, Bz[S], nZb, 0,0,0); \
    nRb = __builtin_amdgcn_mfma_f32_16x16x32_bf16(XSB, Br[S], nRb, 0,0,0); \
    nXb = __builtin_amdgcn_mfma_f32_16x16x32_bf16(XSB, Bh[S], nXb, 0,0,0); \
    ivec8 afA = __builtin_shufflevector(aloA, ahiA, 0,1,2,3,4,5,6,7); \
    ivec8 afB = __builtin_shufflevector(aloB, ahiB, 0,1,2,3,4,5,6,7); \
    fvec4 aZ = __builtin_amdgcn_mfma_scale_f32_16x16x128_f8f6f4(afA, Qz, ZF, 0,0,0, 0x7F7F7F7F, 0, 0x7F7F7F7F); \
    fvec4 aR = __builtin_amdgcn_mfma_scale_f32_16x16x128_f8f6f4(afA, Qr, ZF, 0,0,0, 0x7F7F7F7F, 0, 0x7F7F7F7F); \
    fvec4 aU = __builtin_amdgcn_mfma_scale_f32_16x16x128_f8f6f4(afA, Qh, ZF, 0,0,0, 0x7F7F7F7F, 0, 0x7F7F7F7F); \
    fvec4 bZ = __builtin_amdgcn_mfma_scale_f32_16x16x128_f8f6f4(afB, Qz, ZF, 0,0,0, 0x7F7F7F7F, 0, 0x7F7F7F7F); \
    fvec4 bR = __builtin_amdgcn_mfma_scale_f32_16x16x128_f8f6f4(afB, Qr, ZF, 0,0,0, 0x7F7F7F7F, 0, 0x7F7F7F7F); \
    fvec4 bU = __builtin_amdgcn_mfma_scale_f32_16x16x128_f8f6f4(afB, Qh, ZF, 0,0,0, 0x7F7F7F7F, 0, 0x7F7F7F7F); \
    GATE(xZa, xRa, xXa, aZ, aR, aU, h0a, wbA) \
    GATE(xZb, xRb, xXb, bZ, bR, bU, h0b, wbB) \
    asm volatile("s_waitcnt lgkmcnt(0)" ::: "memory"); \
    __builtin_amdgcn_s_barrier(); \
  }

  for (int g = 0; g < 128; ++g){
    STEPX(0, 0, xs0a, xs0b)
    xs0a = LDS8(tokA1, 2); xs0b = LDS8(tokB1, 2);     // slice 2, used step 2
    STEPX(1, 4096, xs1a, xs1b)
    xs1a = LDS8(tokA1, 3); xs1b = LDS8(tokB1, 3);     // slice 3, used step 3
    STEPX(2, 0, xs0a, xs0b)
    xs0a = LDS8(tokA2, 0); xs0b = LDS8(tokB2, 0);     // next-token slice 0
    STEPX(3, 4096, xs1a, xs1b)
    xs1a = LDS8(tokA2, 1); xs1b = LDS8(tokB2, 1);     // next-token slice 1
    tokA1 = tokA2; tokB1 = tokB2;
    tokA2 = tokens[tbxa + tix(4 * (g + 3) + srow)];
    tokB2 = tokens[tbxb + tix(4 * (g + 3) + srow)];
    xZa = nZa; xRa = nRa; xXa = nXa;  xZb = nZb; xRb = nRb; xXb = nXb;
    nZa = (fvec4){bzs,bzs,bzs,bzs}; nRa = (fvec4){brs,brs,brs,brs}; nXa = (fvec4){bix,bix,bix,bix};
    nZb = (fvec4){bzs,bzs,bzs,bzs}; nRb = (fvec4){brs,brs,brs,brs}; nXb = (fvec4){bix,bix,bix,bix};
  }
#undef STEPX
#undef GATE
#undef LDS8

  // final state: lanes l4<2 hold real batches (tile rows 0,4) of each chain
  if (l4 < 2){
    hbuf[(size_t)(grp * 4 + l4) * 256 + dir * 128 + cw] = h0a;
    hbuf[(size_t)(grp * 4 + 2 + l4) * 256 + dir * 128 + cw] = h0b;
  }
}

// ---------------- head: sigmoid(hcat @ Wd + bd) ----------------
__global__ void head_k(const float* __restrict__ hbuf, const float* __restrict__ Wd,
                       const float* __restrict__ bd, float* __restrict__ out){
  const int wid = threadIdx.x >> 6, lane = threadIdx.x & 63;
  const int b = blockIdx.x * 4 + wid;
  const float* hr = hbuf + (size_t)b * 256;
  float s = 0.f;
#pragma unroll
  for (int j = 0; j < 4; ++j){ const int k = j * 64 + lane; s += hr[k] * Wd[k]; }
#pragma unroll
  for (int off = 32; off > 0; off >>= 1) s += __shfl_down(s, off);
  if (lane == 0) out[b] = 1.f / (1.f + __expf(-(s + bd[0])));
}

extern "C" void kernel_launch(void* const* d_in, const int* in_sizes, int n_in,
                              void* d_out, int out_size, void* d_ws, size_t ws_size,
                              hipStream_t stream){
  const int*   tokens = (const int*)  d_in[0];
  const float* emb    = (const float*)d_in[1];
  const float* Wf     = (const float*)d_in[2];
  const float* Uf     = (const float*)d_in[3];
  const float* bf_    = (const float*)d_in[4];
  const float* Wb     = (const float*)d_in[5];
  const float* Ub     = (const float*)d_in[6];
  const float* bb_    = (const float*)d_in[7];
  const float* Wd     = (const float*)d_in[8];
  const float* bd     = (const float*)d_in[9];
  float* out = (float*)d_out;

  unsigned short* embb = (unsigned short*)d_ws;                       // 12.8 MB bf16 table
  float* hbuf = (float*)((char*)d_ws + (size_t)VOC * HD * sizeof(unsigned short)); // 512 KB

  const int n4 = VOC * HD / 4;
  emb_cvt<<<(n4 + 255) / 256, 256, 0, stream>>>(emb, embb, n4);
  gru_scan<<<256, 512, 0, stream>>>(tokens, embb, Wf, Uf, bf_, Wb, Ub, bb_, hbuf);
  head_k<<<128, 256, 0, stream>>>(hbuf, Wd, bd, out);
}

// Round 8
// 212.758 us; speedup vs baseline: 4.8807x; 1.7378x over previous
//
#include <hip/hip_runtime.h>

#define TLEN 512
#define HD 128
#define VOC 50000

typedef short bvec8 __attribute__((ext_vector_type(8)));   // 8 bf16 (4 VGPRs)
typedef float fvec4 __attribute__((ext_vector_type(4)));   // f32 MFMA accumulator
typedef int   ivec4 __attribute__((ext_vector_type(4)));   // 16B LDS read
typedef int   ivec8 __attribute__((ext_vector_type(8)));   // 32 fp8 = f8f6f4 operand

// xp LDS layout strides (bytes): [slot][step][gate][batch(pad)][col]
#define XPB   8192      // xp region base (after h dbuf)
#define BSTR  532       // batch stride (133 words -> ~2-way banks)
#define GSTR  2128      // gate stride  = 4*BSTR
#define SSTR  6384      // step stride  = 3*GSTR
#define SLOT  25536     // slot stride  = 4*SSTR

__device__ __forceinline__ unsigned short f2bf(float f){
  unsigned u = __builtin_bit_cast(unsigned, f);
  u += 0x7fffu + ((u >> 16) & 1u);
  return (unsigned short)(u >> 16);
}

__device__ __forceinline__ float fsig(float a){
  return __builtin_amdgcn_rcpf(1.f + __builtin_amdgcn_exp2f(-1.44269504f * a));
}

// ---------------- emb fp32 -> bf16 table ----------------
__global__ void emb_cvt(const float* __restrict__ emb, unsigned short* __restrict__ out, int n4){
  int i = blockIdx.x * blockDim.x + threadIdx.x;
  if (i < n4){
    float4 v = *(const float4*)(emb + (size_t)i * 4);
    ushort4 o;
    o.x = f2bf(v.x); o.y = f2bf(v.y); o.z = f2bf(v.z); o.w = f2bf(v.w);
    *(ushort4*)(out + (size_t)i * 4) = o;
  }
}

// ---------------- producer/consumer bidirectional GRU scan ----------------
// 256 blocks (0..127 fwd, 128..255 bwd), 4 batches each, 512 threads = 8 waves.
// Waves 0..3 CONSUMERS: wave w owns gate cols [w*32, w*32+32) (2 col-tiles);
//   per step: 2 ds_read_b128 (h fp8) + 6 xp f32 reads + 6 mfma_scale fp8 K=128
//   + 2 gates + 2 h byte-writes.  Recurrence chain only.
// Waves 4..7 PRODUCERS: wave p owns col-tiles {2p,2p+1}; computes xp=x@W+bi for
//   group g+1 (4 steps packed as A-rows, all 16 rows valid) into LDS slot
//   (g&1)^1 while consumers run group g. 6 bf16 MFMAs per interval.
// One C + one P wave per SIMD -> producer issue fills consumer latency bubbles.
// VGPR union needs the 2-waves/SIMD band (cap 256) -- do NOT tighten bounds.
__global__ __launch_bounds__(512, 2) void gru_scan(
    const int* __restrict__ tokens, const unsigned short* __restrict__ embb,
    const float* __restrict__ Wf, const float* __restrict__ Uf, const float* __restrict__ bfv,
    const float* __restrict__ Wb, const float* __restrict__ Ub, const float* __restrict__ bbv,
    float* __restrict__ hbuf)
{
  const int tid  = threadIdx.x;
  const int wid  = tid >> 6, lane = tid & 63;
  const int l15  = lane & 15, l4 = lane >> 4;
  const int dir  = blockIdx.x >> 7, grp = blockIdx.x & 127;

  const float* __restrict__ W  = dir ? Wb : Wf;
  const float* __restrict__ U  = dir ? Ub : Uf;
  const float* __restrict__ bv = dir ? bbv : bfv;

  // [0,8192): h fp8 dbuf (16 rows x 144B at 0 and 4096); [8192, 8192+2*25536): xp
  __shared__ __attribute__((aligned(16))) unsigned char hl[59392];

  const bool cons = (wid < 4);
  const fvec4 ZF = {0.f, 0.f, 0.f, 0.f};

  for (int i = tid; i < 2048; i += 512) ((int*)hl)[i] = 0;   // zero h dbuf

  // ---------------- consumer state ----------------
  ivec8 Qz0, Qr0, Qh0, Qz1, Qr1, Qh1;
  float buh0 = 0.f, buh1 = 0.f, h0a = 0.f, h0b = 0.f;
  const int hrd = l15 * 144 + l4 * 32;
  int wb0 = 0, wb1 = 0, xco0 = 0, xco1 = 0;

  // ---------------- producer state ----------------
  bvec8 Pz[2][4], Pr[2][4], Ph[2][4];
  bvec8 xc[4];
  fvec4 az = ZF, ar_ = ZF, ax = ZF;            // persist across intervals (tile-major)
  float bz[2] = {0,0}, br[2] = {0,0}, bx[2] = {0,0};
  long tbx = 0; int t2tok = 0, cu4[2] = {0,0};

  const int brow = l15 >> 2, srow = l15 & 3;
  const int tb0 = dir ? (TLEN - 1) : 0, tsg = dir ? -1 : 1;
  auto tix = [&](int t){ t = (t > TLEN - 1) ? (TLEN - 1) : t; return tb0 + tsg * t; };
#define LDS8(tok, sl) (*(const bvec8*)(embb + (size_t)(tok) * HD + (sl) * 32 + l4 * 8))

  if (cons){
    const int cw0 = wid * 32 + l15, cw1 = cw0 + 16;
#pragma unroll
    for (int w = 0; w < 8; ++w){
      const int k0 = l4 * 32 + w * 4;
      int v;
      v = __builtin_amdgcn_cvt_pk_fp8_f32(U[(k0+0)*384 + cw0],       U[(k0+1)*384 + cw0],       0, 0);
      Qz0[w] = __builtin_amdgcn_cvt_pk_fp8_f32(U[(k0+2)*384 + cw0],  U[(k0+3)*384 + cw0],       v, 1);
      v = __builtin_amdgcn_cvt_pk_fp8_f32(U[(k0+0)*384 + 128 + cw0], U[(k0+1)*384 + 128 + cw0], 0, 0);
      Qr0[w] = __builtin_amdgcn_cvt_pk_fp8_f32(U[(k0+2)*384 + 128 + cw0], U[(k0+3)*384 + 128 + cw0], v, 1);
      v = __builtin_amdgcn_cvt_pk_fp8_f32(U[(k0+0)*384 + 256 + cw0], U[(k0+1)*384 + 256 + cw0], 0, 0);
      Qh0[w] = __builtin_amdgcn_cvt_pk_fp8_f32(U[(k0+2)*384 + 256 + cw0], U[(k0+3)*384 + 256 + cw0], v, 1);
      v = __builtin_amdgcn_cvt_pk_fp8_f32(U[(k0+0)*384 + cw1],       U[(k0+1)*384 + cw1],       0, 0);
      Qz1[w] = __builtin_amdgcn_cvt_pk_fp8_f32(U[(k0+2)*384 + cw1],  U[(k0+3)*384 + cw1],       v, 1);
      v = __builtin_amdgcn_cvt_pk_fp8_f32(U[(k0+0)*384 + 128 + cw1], U[(k0+1)*384 + 128 + cw1], 0, 0);
      Qr1[w] = __builtin_amdgcn_cvt_pk_fp8_f32(U[(k0+2)*384 + 128 + cw1], U[(k0+3)*384 + 128 + cw1], v, 1);
      v = __builtin_amdgcn_cvt_pk_fp8_f32(U[(k0+0)*384 + 256 + cw1], U[(k0+1)*384 + 256 + cw1], 0, 0);
      Qh1[w] = __builtin_amdgcn_cvt_pk_fp8_f32(U[(k0+2)*384 + 256 + cw1], U[(k0+3)*384 + 256 + cw1], v, 1);
    }
    buh0 = bv[384 + 256 + cw0]; buh1 = bv[384 + 256 + cw1];
    wb0 = (4 * l4) * 144 + cw0; wb1 = wb0 + 16;
    xco0 = l4 * BSTR + cw0 * 4; xco1 = xco0 + 64;
  } else {
    const int p = wid - 4;
    tbx = (long)(grp * 4 + brow) * TLEN;
#pragma unroll
    for (int u = 0; u < 2; ++u){
      const int cu = p * 32 + u * 16 + l15;
      cu4[u] = cu * 4;
#pragma unroll
      for (int kt = 0; kt < 4; ++kt){
#pragma unroll
        for (int j = 0; j < 8; ++j){
          const int k = kt * 32 + l4 * 8 + j;
          Pz[u][kt][j] = (short)f2bf(W[k * 384 + cu]);
          Pr[u][kt][j] = (short)f2bf(W[k * 384 + 128 + cu]);
          Ph[u][kt][j] = (short)f2bf(W[k * 384 + 256 + cu]);
        }
      }
      bz[u] = bv[cu] + bv[384 + cu];
      br[u] = bv[128 + cu] + bv[384 + 128 + cu];
      bx[u] = bv[256 + cu];
    }
    // ---- prologue: fill xp slot 0 (group 0) ----
    {
      const int t0 = tokens[tbx + tix(srow)];
      bvec8 xg[4];
#pragma unroll
      for (int kt = 0; kt < 4; ++kt) xg[kt] = LDS8(t0, kt);
#pragma unroll
      for (int u = 0; u < 2; ++u){
        az  = (fvec4){bz[u], bz[u], bz[u], bz[u]};
        ar_ = (fvec4){br[u], br[u], br[u], br[u]};
        ax  = (fvec4){bx[u], bx[u], bx[u], bx[u]};
#pragma unroll
        for (int kt = 0; kt < 4; ++kt){
          az  = __builtin_amdgcn_mfma_f32_16x16x32_bf16(xg[kt], Pz[u][kt], az,  0,0,0);
          ar_ = __builtin_amdgcn_mfma_f32_16x16x32_bf16(xg[kt], Pr[u][kt], ar_, 0,0,0);
          ax  = __builtin_amdgcn_mfma_f32_16x16x32_bf16(xg[kt], Ph[u][kt], ax,  0,0,0);
        }
#pragma unroll
        for (int s = 0; s < 4; ++s){
          const int ba = XPB + s * SSTR + l4 * BSTR + cu4[u];
          *(float*)&hl[ba]            = az[s];
          *(float*)&hl[ba + GSTR]     = ar_[s];
          *(float*)&hl[ba + 2 * GSTR] = ax[s];
        }
      }
      const int t1 = tokens[tbx + tix(4 + srow)];
#pragma unroll
      for (int kt = 0; kt < 4; ++kt) xc[kt] = LDS8(t1, kt);
      t2tok = tokens[tbx + tix(8 + srow)];
    }
  }
  __syncthreads();

#define BAR do{ asm volatile("s_waitcnt lgkmcnt(0)" ::: "memory"); __builtin_amdgcn_s_barrier(); }while(0)

#define MFS(A, B) __builtin_amdgcn_mfma_scale_f32_16x16x128_f8f6f4(A, B, ZF, 0, 0, 0, 0x7F7F7F7F, 0, 0x7F7F7F7F)

#define GATE1(XZ, XR, XX, AZ, AR, AU, BUH, H, WS) { \
    float zz = fsig((XZ) + AZ[0]); \
    float rg = fsig((XR) + AR[0]); \
    float arr = (XX) + rg * (AU[0] + (BUH)); arr = fmaxf(arr, -30.f); \
    float y  = __builtin_amdgcn_exp2f(-2.88539008f * arr); \
    float th = (1.f - y) * __builtin_amdgcn_rcpf(1.f + y); \
    H = th + zz * (H - th); \
    hl[PX + (WS)] = (unsigned char)(__builtin_amdgcn_cvt_pk_fp8_f32(H, H, 0, 0) & 0xff); }

#define CSTEP(S, P, XR) { \
    const int PX = (P) ^ 4096; \
    ivec4 alo = *(const ivec4*)&hl[(P) + hrd]; \
    ivec4 ahi = *(const ivec4*)&hl[(P) + hrd + 16]; \
    float xz0 = *(const float*)&hl[(XR) + (S)*SSTR + xco0]; \
    float xr0 = *(const float*)&hl[(XR) + (S)*SSTR + GSTR + xco0]; \
    float xx0 = *(const float*)&hl[(XR) + (S)*SSTR + 2*GSTR + xco0]; \
    float xz1 = *(const float*)&hl[(XR) + (S)*SSTR + xco1]; \
    float xr1 = *(const float*)&hl[(XR) + (S)*SSTR + GSTR + xco1]; \
    float xx1 = *(const float*)&hl[(XR) + (S)*SSTR + 2*GSTR + xco1]; \
    ivec8 af = __builtin_shufflevector(alo, ahi, 0,1,2,3,4,5,6,7); \
    fvec4 aZ0 = MFS(af, Qz0); fvec4 aR0 = MFS(af, Qr0); fvec4 aU0 = MFS(af, Qh0); \
    fvec4 aZ1 = MFS(af, Qz1); fvec4 aR1 = MFS(af, Qr1); fvec4 aU1 = MFS(af, Qh1); \
    GATE1(xz0, xr0, xx0, aZ0, aR0, aU0, buh0, h0a, wb0) \
    GATE1(xz1, xr1, xx1, aZ1, aR1, aU1, buh1, h0b, wb1) \
  }

#define PMM(U_, KT) { \
    az  = __builtin_amdgcn_mfma_f32_16x16x32_bf16(xc[KT], Pz[U_][KT], az,  0,0,0); \
    ar_ = __builtin_amdgcn_mfma_f32_16x16x32_bf16(xc[KT], Pr[U_][KT], ar_, 0,0,0); \
    ax  = __builtin_amdgcn_mfma_f32_16x16x32_bf16(xc[KT], Ph[U_][KT], ax,  0,0,0); }

#define PWR1(U_, XW, S) { \
    const int ba = (XW) + (S)*SSTR + l4*BSTR + cu4[U_]; \
    *(float*)&hl[ba]          = az[S]; \
    *(float*)&hl[ba + GSTR]   = ar_[S]; \
    *(float*)&hl[ba + 2*GSTR] = ax[S]; }

  for (int g = 0; g < 128; ++g){
    const int XR = XPB + (g & 1) * SLOT;            // consumer read slot (group g)
    const int XW = XPB + ((g & 1) ^ 1) * SLOT;      // producer write slot (group g+1)
    if (cons){ CSTEP(0, 0, XR) }
    else {
      az  = (fvec4){bz[0], bz[0], bz[0], bz[0]};
      ar_ = (fvec4){br[0], br[0], br[0], br[0]};
      ax  = (fvec4){bx[0], bx[0], bx[0], bx[0]};
      PMM(0, 0) PMM(0, 1)
    }
    BAR;
    if (cons){ CSTEP(1, 4096, XR) }
    else { PMM(0, 2) PMM(0, 3) PWR1(0, XW, 0) PWR1(0, XW, 1) PWR1(0, XW, 2) PWR1(0, XW, 3) }
    BAR;
    if (cons){ CSTEP(2, 0, XR) }
    else {
      az  = (fvec4){bz[1], bz[1], bz[1], bz[1]};
      ar_ = (fvec4){br[1], br[1], br[1], br[1]};
      ax  = (fvec4){bx[1], bx[1], bx[1], bx[1]};
      PMM(1, 0) PMM(1, 1)
      xc[0] = LDS8(t2tok, 0); xc[1] = LDS8(t2tok, 1);   // frags for group g+2
    }
    BAR;
    if (cons){ CSTEP(3, 4096, XR) }
    else {
      PMM(1, 2) PMM(1, 3) PWR1(1, XW, 0) PWR1(1, XW, 1) PWR1(1, XW, 2) PWR1(1, XW, 3)
      xc[2] = LDS8(t2tok, 2); xc[3] = LDS8(t2tok, 3);
      t2tok = tokens[tbx + tix(4 * (g + 3) + srow)];
    }
    BAR;
  }
#undef CSTEP
#undef GATE1
#undef PMM
#undef PWR1
#undef MFS
#undef BAR
#undef LDS8

  // final state -> hbuf[512][256], fwd cols 0..127, bwd cols 128..255
  if (cons){
    const int cw0 = wid * 32 + l15, cw1 = cw0 + 16;
    hbuf[(size_t)(grp * 4 + l4) * 256 + dir * 128 + cw0] = h0a;
    hbuf[(size_t)(grp * 4 + l4) * 256 + dir * 128 + cw1] = h0b;
  }
}

// ---------------- head: sigmoid(hcat @ Wd + bd) ----------------
__global__ void head_k(const float* __restrict__ hbuf, const float* __restrict__ Wd,
                       const float* __restrict__ bd, float* __restrict__ out){
  const int wid = threadIdx.x >> 6, lane = threadIdx.x & 63;
  const int b = blockIdx.x * 4 + wid;
  const float* hr = hbuf + (size_t)b * 256;
  float s = 0.f;
#pragma unroll
  for (int j = 0; j < 4; ++j){ const int k = j * 64 + lane; s += hr[k] * Wd[k]; }
#pragma unroll
  for (int off = 32; off > 0; off >>= 1) s += __shfl_down(s, off);
  if (lane == 0) out[b] = 1.f / (1.f + __expf(-(s + bd[0])));
}

extern "C" void kernel_launch(void* const* d_in, const int* in_sizes, int n_in,
                              void* d_out, int out_size, void* d_ws, size_t ws_size,
                              hipStream_t stream){
  const int*   tokens = (const int*)  d_in[0];
  const float* emb    = (const float*)d_in[1];
  const float* Wf     = (const float*)d_in[2];
  const float* Uf     = (const float*)d_in[3];
  const float* bf_    = (const float*)d_in[4];
  const float* Wb     = (const float*)d_in[5];
  const float* Ub     = (const float*)d_in[6];
  const float* bb_    = (const float*)d_in[7];
  const float* Wd     = (const float*)d_in[8];
  const float* bd     = (const float*)d_in[9];
  float* out = (float*)d_out;

  unsigned short* embb = (unsigned short*)d_ws;                       // 12.8 MB bf16 table
  float* hbuf = (float*)((char*)d_ws + (size_t)VOC * HD * sizeof(unsigned short)); // 512 KB

  const int n4 = VOC * HD / 4;
  emb_cvt<<<(n4 + 255) / 256, 256, 0, stream>>>(emb, embb, n4);
  gru_scan<<<256, 512, 0, stream>>>(tokens, embb, Wf, Uf, bf_, Wb, Ub, bb_, hbuf);
  head_k<<<128, 256, 0, stream>>>(hbuf, Wd, bd, out);
}

// Round 9
// 190.651 us; speedup vs baseline: 5.4467x; 1.1160x over previous
//
#include <hip/hip_runtime.h>

#define TLEN 512
#define HD 128
#define VOC 50000

typedef float fvec4 __attribute__((ext_vector_type(4)));   // f32 MFMA accumulator
typedef int   ivec4 __attribute__((ext_vector_type(4)));   // 16B LDS read
typedef int   ivec8 __attribute__((ext_vector_type(8)));   // 32 fp8 = f8f6f4 operand

__device__ __forceinline__ float fsig(float a){
  return __builtin_amdgcn_rcpf(1.f + __builtin_amdgcn_exp2f(-1.44269504f * a));
}

// ---------------- emb fp32 -> fp8 e4m3 (x16 scale) table ----------------
__global__ void emb_cvt8(const float* __restrict__ emb, int* __restrict__ out, int n4){
  int i = blockIdx.x * blockDim.x + threadIdx.x;
  if (i < n4){
    float4 v = *(const float4*)(emb + (size_t)i * 4);
    int p = __builtin_amdgcn_cvt_pk_fp8_f32(16.f * v.x, 16.f * v.y, 0, 0);
    p     = __builtin_amdgcn_cvt_pk_fp8_f32(16.f * v.z, 16.f * v.w, p, 1);
    out[i] = p;
  }
}

// ---------------- persistent bidirectional GRU scan: 4-wave all-fp8 ----------------
// 256 blocks (1/CU via 96KB LDS claim): 0..127 fwd, 128..255 bwd; 4 batches each.
// 256 threads = 4 waves = 1 wave/SIMD (no lockstep contention). Wave w owns gate
// cols {w*32+2*l15, +1} (sigma-permutation -> adjacent b16 h-write per lane).
// Recurrence h@U AND input-proj x@W both use mfma_scale 16x16x128 fp8: xp packed
// 4 timesteps/tile lands in the exact acc element the gate reads (batch l4, step s)
// -> ZERO LDS for xp. All fp8 stored x16, block-scale 2^-4 on A and B (exact net 1).
// Per step per wave: 2 ds_read_b128 (h) + 6 rec MFS + ~1.5 woven xp MFS + 2 gates
// + 1 b16 write + 1 barrier (4 waves).
__global__ __launch_bounds__(256, 1) void gru_scan(
    const int* __restrict__ tokens, const unsigned char* __restrict__ embq,
    const float* __restrict__ Wf, const float* __restrict__ Uf, const float* __restrict__ bfv,
    const float* __restrict__ Wb, const float* __restrict__ Ub, const float* __restrict__ bbv,
    float* __restrict__ hbuf)
{
  const int tid  = threadIdx.x;
  const int wid  = tid >> 6, lane = tid & 63;
  const int l15  = lane & 15, l4 = lane >> 4;
  const int dir  = blockIdx.x >> 7, grp = blockIdx.x & 127;
  const int c0   = wid * 32 + 2 * l15, c1 = c0 + 1;   // owned gate columns

  const float* __restrict__ W  = dir ? Wb : Wf;
  const float* __restrict__ U  = dir ? Ub : Uf;
  const float* __restrict__ bv = dir ? bbv : bfv;

  // claim 96KB -> 1 block/CU; use 8KB: h fp8 dbuf (16 rows x 144B) at 0 and 4096
  __shared__ __attribute__((aligned(16))) unsigned char hl[98304];

  // fp8 B-frags (x16): lane (l4,l15) holds col-index l15 -> our chosen col, k=l4*32+j
  auto pack8 = [&](const float* M, int col)->ivec8{
    ivec8 q;
#pragma unroll
    for (int w = 0; w < 8; ++w){
      const int k0 = l4 * 32 + w * 4;
      int v = __builtin_amdgcn_cvt_pk_fp8_f32(16.f*M[(k0+0)*384 + col], 16.f*M[(k0+1)*384 + col], 0, 0);
      q[w]  = __builtin_amdgcn_cvt_pk_fp8_f32(16.f*M[(k0+2)*384 + col], 16.f*M[(k0+3)*384 + col], v, 1);
    }
    return q;
  };
  const ivec8 Qz0 = pack8(U, c0), Qr0 = pack8(U, 128 + c0), Qh0 = pack8(U, 256 + c0);
  const ivec8 Qz1 = pack8(U, c1), Qr1 = pack8(U, 128 + c1), Qh1 = pack8(U, 256 + c1);
  const ivec8 Pz0 = pack8(W, c0), Pr0 = pack8(W, 128 + c0), Ph0 = pack8(W, 256 + c0);
  const ivec8 Pz1 = pack8(W, c1), Pr1 = pack8(W, 128 + c1), Ph1 = pack8(W, 256 + c1);

  // biases: z/r fully folded into xp C-input; hh: input bias in xp C, recurrent in rec C
  const float bz0 = bv[c0] + bv[384 + c0], br0 = bv[128 + c0] + bv[384 + 128 + c0];
  const float bx0 = bv[256 + c0],          bu0 = bv[384 + 256 + c0];
  const float bz1 = bv[c1] + bv[384 + c1], br1 = bv[128 + c1] + bv[384 + 128 + c1];
  const float bx1 = bv[256 + c1],          bu1 = bv[384 + 256 + c1];
  const fvec4 CZ0 = {bz0,bz0,bz0,bz0}, CR0 = {br0,br0,br0,br0}, CX0 = {bx0,bx0,bx0,bx0};
  const fvec4 CZ1 = {bz1,bz1,bz1,bz1}, CR1 = {br1,br1,br1,br1}, CX1 = {bx1,bx1,bx1,bx1};
  const fvec4 CU0 = {bu0,bu0,bu0,bu0}, CU1 = {bu1,bu1,bu1,bu1};
  const fvec4 ZF  = {0.f,0.f,0.f,0.f};

  for (int i = tid; i < 2048; i += 256) ((int*)hl)[i] = 0;   // zero both h buffers
  float h0a = 0.f, h0b = 0.f;        // h[batch l4][c0], h[batch l4][c1] fp32 master

  // x A-frag: tile row l15 = (batch l15>>2, step l15&3); lane reads 32B of fp8 emb row
  const int  brow = l15 >> 2, srow = l15 & 3;
  const long tbx  = (long)(grp * 4 + brow) * TLEN;
  const int  tb0  = dir ? (TLEN - 1) : 0, tsg = dir ? -1 : 1;
  auto tix = [&](int t){ t = (t > TLEN - 1) ? (TLEN - 1) : t; return tb0 + tsg * t; };
#define XLD(tok) (*(const ivec8*)(embq + (size_t)(tok) * HD + l4 * 32))
#define MFS(A, B, C) __builtin_amdgcn_mfma_scale_f32_16x16x128_f8f6f4(A, B, C, 0, 0, 0, 0x7B7B7B7B, 0, 0x7B7B7B7B)

  // prologue: xp(group 0) direct; x-frag for group 1; token for group 2
  fvec4 eZ0, eR0, eX0, eZ1, eR1, eX1, oZ0, oR0, oX0, oZ1, oR1, oX1;
  ivec8 xfa, xfb;
  {
    const int t0 = tokens[tbx + tix(srow)];
    ivec8 xf0 = XLD(t0);
    eZ0 = MFS(xf0, Pz0, CZ0); eR0 = MFS(xf0, Pr0, CR0); eX0 = MFS(xf0, Ph0, CX0);
    eZ1 = MFS(xf0, Pz1, CZ1); eR1 = MFS(xf0, Pr1, CR1); eX1 = MFS(xf0, Ph1, CX1);
    const int t1 = tokens[tbx + tix(4 + srow)];
    xfa = XLD(t1);
  }
  int tok2 = tokens[tbx + tix(8 + srow)];

  const int hrd = l15 * 144 + l4 * 32;                 // h A-frag base (byte)
  const int wb  = (4 * l4) * 144 + c0;                 // b16 h write slot (byte)
  __syncthreads();

#define STEP(S, P, XZ0, XR0, XX0, XZ1, XR1, XX1, WV) { \
    ivec4 alo = *(const ivec4*)&hl[(P) + hrd]; \
    ivec4 ahi = *(const ivec4*)&hl[(P) + hrd + 16]; \
    WV \
    ivec8 af = __builtin_shufflevector(alo, ahi, 0,1,2,3,4,5,6,7); \
    fvec4 aZ0 = MFS(af, Qz0, ZF); \
    fvec4 aR0 = MFS(af, Qr0, ZF); \
    fvec4 aU0 = MFS(af, Qh0, CU0); \
    fvec4 aZ1 = MFS(af, Qz1, ZF); \
    fvec4 aR1 = MFS(af, Qr1, ZF); \
    fvec4 aU1 = MFS(af, Qh1, CU1); \
    float z0 = fsig(XZ0[S] + aZ0[0]); \
    float r0 = fsig(XR0[S] + aR0[0]); \
    float a0 = XX0[S] + r0 * aU0[0]; a0 = fmaxf(a0, -30.f); \
    float y0 = __builtin_amdgcn_exp2f(-2.88539008f * a0); \
    float t0 = (1.f - y0) * __builtin_amdgcn_rcpf(1.f + y0); \
    h0a = t0 + z0 * (h0a - t0); \
    float z1 = fsig(XZ1[S] + aZ1[0]); \
    float r1 = fsig(XR1[S] + aR1[0]); \
    float a1 = XX1[S] + r1 * aU1[0]; a1 = fmaxf(a1, -30.f); \
    float y1 = __builtin_amdgcn_exp2f(-2.88539008f * a1); \
    float t1 = (1.f - y1) * __builtin_amdgcn_rcpf(1.f + y1); \
    h0b = t1 + z1 * (h0b - t1); \
    *(unsigned short*)&hl[((P) ^ 4096) + wb] = \
        (unsigned short)(__builtin_amdgcn_cvt_pk_fp8_f32(16.f * h0a, 16.f * h0b, 0, 0) & 0xffff); \
    asm volatile("s_waitcnt lgkmcnt(0)" ::: "memory"); \
    __builtin_amdgcn_s_barrier(); \
}

  for (int g = 0; g < 128; g += 2){
    // even group: gates from E accs; weave O := xp(g+1) from xfa; reload xfb <- x(g+2)
    STEP(0, 0,    eZ0,eR0,eX0,eZ1,eR1,eX1,
         { oZ0 = MFS(xfa, Pz0, CZ0); oR0 = MFS(xfa, Pr0, CR0);
           xfb = XLD(tok2); tok2 = tokens[tbx + tix(4 * (g + 3) + srow)]; })
    STEP(1, 4096, eZ0,eR0,eX0,eZ1,eR1,eX1,
         { oX0 = MFS(xfa, Ph0, CX0); oZ1 = MFS(xfa, Pz1, CZ1); })
    STEP(2, 0,    eZ0,eR0,eX0,eZ1,eR1,eX1,
         { oR1 = MFS(xfa, Pr1, CR1); oX1 = MFS(xfa, Ph1, CX1); })
    STEP(3, 4096, eZ0,eR0,eX0,eZ1,eR1,eX1, { })
    // odd group: gates from O accs; weave E := xp(g+2) from xfb; reload xfa <- x(g+3)
    STEP(0, 0,    oZ0,oR0,oX0,oZ1,oR1,oX1,
         { eZ0 = MFS(xfb, Pz0, CZ0); eR0 = MFS(xfb, Pr0, CR0);
           xfa = XLD(tok2); tok2 = tokens[tbx + tix(4 * (g + 4) + srow)]; })
    STEP(1, 4096, oZ0,oR0,oX0,oZ1,oR1,oX1,
         { eX0 = MFS(xfb, Ph0, CX0); eZ1 = MFS(xfb, Pz1, CZ1); })
    STEP(2, 0,    oZ0,oR0,oX0,oZ1,oR1,oX1,
         { eR1 = MFS(xfb, Pr1, CR1); eX1 = MFS(xfb, Ph1, CX1); })
    STEP(3, 4096, oZ0,oR0,oX0,oZ1,oR1,oX1, { })
  }
#undef STEP
#undef MFS
#undef XLD

  // final state -> hbuf[512][256], fwd cols 0..127, bwd cols 128..255
  hbuf[(size_t)(grp * 4 + l4) * 256 + dir * 128 + c0] = h0a;
  hbuf[(size_t)(grp * 4 + l4) * 256 + dir * 128 + c1] = h0b;
}

// ---------------- head: sigmoid(hcat @ Wd + bd) ----------------
__global__ void head_k(const float* __restrict__ hbuf, const float* __restrict__ Wd,
                       const float* __restrict__ bd, float* __restrict__ out){
  const int wid = threadIdx.x >> 6, lane = threadIdx.x & 63;
  const int b = blockIdx.x * 4 + wid;
  const float* hr = hbuf + (size_t)b * 256;
  float s = 0.f;
#pragma unroll
  for (int j = 0; j < 4; ++j){ const int k = j * 64 + lane; s += hr[k] * Wd[k]; }
#pragma unroll
  for (int off = 32; off > 0; off >>= 1) s += __shfl_down(s, off);
  if (lane == 0) out[b] = 1.f / (1.f + __expf(-(s + bd[0])));
}

extern "C" void kernel_launch(void* const* d_in, const int* in_sizes, int n_in,
                              void* d_out, int out_size, void* d_ws, size_t ws_size,
                              hipStream_t stream){
  const int*   tokens = (const int*)  d_in[0];
  const float* emb    = (const float*)d_in[1];
  const float* Wf     = (const float*)d_in[2];
  const float* Uf     = (const float*)d_in[3];
  const float* bf_    = (const float*)d_in[4];
  const float* Wb     = (const float*)d_in[5];
  const float* Ub     = (const float*)d_in[6];
  const float* bb_    = (const float*)d_in[7];
  const float* Wd     = (const float*)d_in[8];
  const float* bd     = (const float*)d_in[9];
  float* out = (float*)d_out;

  unsigned char* embq = (unsigned char*)d_ws;                        // 6.4 MB fp8 table
  float* hbuf = (float*)((char*)d_ws + (size_t)VOC * HD);            // 512 KB

  const int n4 = VOC * HD / 4;
  emb_cvt8<<<(n4 + 255) / 256, 256, 0, stream>>>(emb, (int*)embq, n4);
  gru_scan<<<256, 256, 0, stream>>>(tokens, embq, Wf, Uf, bf_, Wb, Ub, bb_, hbuf);
  head_k<<<128, 256, 0, stream>>>(hbuf, Wd, bd, out);
}